// Round 1
// baseline (38.361 us; speedup 1.0000x reference)
//
#include <hip/hip_runtime.h>

// CustomBatchNorm2D forward (training-mode, with the einsum-diag "scale").
// Shapes: x (N=32, C=512, H=32, W=32) f32; gamma,beta (C,) f32.
// Math:
//   mean[c]  = mean over (N,H,W)
//   S[i,c]   = sum_hw x[i,c,hw]
//   s[i,c]   = S[i,c] - HW*mean[c]
//   diag[c]  = sum_i s[i,c]^2 / HW
//   out      = gamma[c]*abs(diag[c])*(x - mean[c]) + beta[c]
//            = A[c]*x + B[c],  A = gamma*abs(diag),  B = beta - A*mean

#define HW_   1024
#define C_    512
#define N_    32

// Kernel 1: one block per (i,c) row; 256 threads x float4 = 1024 elems.
__global__ void __launch_bounds__(256)
persample_sums(const float* __restrict__ x, float* __restrict__ S) {
    const int bid = blockIdx.x;                    // i*C + c
    const float4* xv = reinterpret_cast<const float4*>(x) + (size_t)bid * (HW_ / 4);
    float4 v = xv[threadIdx.x];
    float sum = v.x + v.y + v.z + v.w;
    // wave64 butterfly
    #pragma unroll
    for (int off = 32; off > 0; off >>= 1)
        sum += __shfl_down(sum, off, 64);
    __shared__ float part[4];
    const int lane = threadIdx.x & 63;
    const int wid  = threadIdx.x >> 6;
    if (lane == 0) part[wid] = sum;
    __syncthreads();
    if (threadIdx.x == 0)
        S[bid] = part[0] + part[1] + part[2] + part[3];
}

// Kernel 2: per-channel stats -> fused affine coefficients A[c], B[c].
__global__ void __launch_bounds__(256)
channel_stats(const float* __restrict__ S,
              const float* __restrict__ gamma,
              const float* __restrict__ beta,
              float* __restrict__ AB) {
    const int c = blockIdx.x * blockDim.x + threadIdx.x;
    if (c >= C_) return;
    float total = 0.f;
    #pragma unroll
    for (int i = 0; i < N_; ++i) total += S[i * C_ + c];
    const float mean = total * (1.0f / (float)(N_ * HW_));
    float d = 0.f;
    #pragma unroll
    for (int i = 0; i < N_; ++i) {
        const float s = S[i * C_ + c] - (float)HW_ * mean;
        d += s * s;
    }
    const float diag = d * (1.0f / (float)HW_);
    const float A = gamma[c] * fabsf(diag);
    AB[c]       = A;
    AB[C_ + c]  = beta[c] - A * mean;
}

// Kernel 3: out = A[c]*x + B[c], float4 grid-stride.
__global__ void __launch_bounds__(256)
apply_affine(const float* __restrict__ x, const float* __restrict__ AB,
             float* __restrict__ out) {
    const float4* xv = reinterpret_cast<const float4*>(x);
    float4*       ov = reinterpret_cast<float4*>(out);
    const int nvec = (N_ * C_ * HW_) / 4;          // 4,194,304
    for (int idx = blockIdx.x * blockDim.x + threadIdx.x; idx < nvec;
         idx += gridDim.x * blockDim.x) {
        const int c = (idx >> 8) & (C_ - 1);       // (idx*4 / HW) % C
        const float A = AB[c];
        const float B = AB[C_ + c];
        float4 v = xv[idx];
        float4 o;
        o.x = fmaf(A, v.x, B);
        o.y = fmaf(A, v.y, B);
        o.z = fmaf(A, v.z, B);
        o.w = fmaf(A, v.w, B);
        ov[idx] = o;
    }
}

extern "C" void kernel_launch(void* const* d_in, const int* in_sizes, int n_in,
                              void* d_out, int out_size, void* d_ws, size_t ws_size,
                              hipStream_t stream) {
    const float* x     = (const float*)d_in[0];
    const float* gamma = (const float*)d_in[1];
    const float* beta  = (const float*)d_in[2];
    float*       out   = (float*)d_out;

    float* S  = (float*)d_ws;                 // N_*C_ = 16384 floats
    float* AB = S + (N_ * C_);                // 2*C_  = 1024 floats

    persample_sums<<<N_ * C_, 256, 0, stream>>>(x, S);
    channel_stats<<<2, 256, 0, stream>>>(S, gamma, beta, AB);

    const int nvec = (N_ * C_ * HW_) / 4;
    int blocks = 2048;                        // 8 vec4/thread grid-stride
    apply_affine<<<blocks, 256, 0, stream>>>(x, AB, out);
    (void)in_sizes; (void)n_in; (void)out_size; (void)ws_size; (void)nvec;
}

// Round 3
// 37.274 us; speedup vs baseline: 1.0292x; 1.0292x over previous
//
#include <hip/hip_runtime.h>

// CustomBatchNorm2D forward. x (N=32, C=512, H=32, W=32) f32.
//   S[i,c]  = sum_hw x[i,c,:]
//   mean[c] = sum_i S[i,c] / (N*HW)
//   diag[c] = sum_i (S[i,c] - HW*mean[c])^2 / HW
//   out     = A[c]*x + B[c],  A = gamma[c]*abs(diag[c]),  B = beta[c] - A*mean[c]
//
// Two kernels (no cooperative launch):
//   K1: one wave per (i,c) row -> S.  Pure wave-reduce, no barriers.
//   K2: per block: recompute A/B for its 8 channels from S (cheap, L2-hit),
//       then apply affine to its 8 rows.  x re-read is L3-resident.

#define HW_   1024
#define C_    512
#define N_    32

// K1: 4096 blocks x 256 threads; one 64-lane wave per row, 4 float4/lane.
__global__ void __launch_bounds__(256)
persample_sums(const float* __restrict__ x, float* __restrict__ S) {
    const int gwave = (blockIdx.x * 256 + threadIdx.x) >> 6;  // row = i*C + c
    const int lane  = threadIdx.x & 63;
    const float4* xv = reinterpret_cast<const float4*>(x)
                       + (size_t)gwave * (HW_ / 4);
    float s = 0.f;
    #pragma unroll
    for (int k = 0; k < 4; ++k) {
        const float4 v = xv[lane + 64 * k];
        s += (v.x + v.y) + (v.z + v.w);
    }
    #pragma unroll
    for (int off = 32; off > 0; off >>= 1)
        s += __shfl_down(s, off, 64);
    if (lane == 0) S[gwave] = s;
}

// K2: 2048 blocks x 256 threads; 8 rows (same sample, 8 consecutive channels)
// per block. Phase A: stats for the 8 channels. Phase B: apply.
__global__ void __launch_bounds__(256)
stats_apply(const float* __restrict__ x, const float* __restrict__ S,
            const float* __restrict__ gamma, const float* __restrict__ beta,
            float* __restrict__ out) {
    const int t    = threadIdx.x;
    const int row0 = blockIdx.x * 8;
    const int c0   = row0 & (C_ - 1);

    // Phase A: thread t -> channel cl = t>>5, sample ip = t&31.
    const int cl = t >> 5;
    const int ip = t & 31;
    const int c  = c0 + cl;
    const float sv = S[ip * C_ + c];
    float tot = sv;
    #pragma unroll
    for (int off = 16; off > 0; off >>= 1)
        tot += __shfl_xor(tot, off, 64);       // sum over the 32-lane group
    const float mean  = tot * (1.0f / (float)(N_ * HW_));
    const float m1024 = tot * (1.0f / (float)N_);   // HW * mean
    const float e = sv - m1024;
    float d = e * e;
    #pragma unroll
    for (int off = 16; off > 0; off >>= 1)
        d += __shfl_xor(d, off, 64);

    __shared__ float Av[8], Bv[8];
    if (ip == 0) {
        const float diag = d * (1.0f / (float)HW_);
        const float A = gamma[c] * fabsf(diag);
        Av[cl] = A;
        Bv[cl] = beta[c] - A * mean;
    }
    __syncthreads();

    // Phase B: row k (k=0..7) at float4 position t within the row.
    const float4* xv = reinterpret_cast<const float4*>(x)
                       + (size_t)row0 * (HW_ / 4);
    float4* ov = reinterpret_cast<float4*>(out)
                 + (size_t)row0 * (HW_ / 4);
    #pragma unroll
    for (int k = 0; k < 8; ++k) {
        const float A = Av[k], B = Bv[k];
        const float4 v = xv[t + 256 * k];
        float4 o;
        o.x = fmaf(A, v.x, B);
        o.y = fmaf(A, v.y, B);
        o.z = fmaf(A, v.z, B);
        o.w = fmaf(A, v.w, B);
        ov[t + 256 * k] = o;
    }
}

extern "C" void kernel_launch(void* const* d_in, const int* in_sizes, int n_in,
                              void* d_out, int out_size, void* d_ws, size_t ws_size,
                              hipStream_t stream) {
    const float* x     = (const float*)d_in[0];
    const float* gamma = (const float*)d_in[1];
    const float* beta  = (const float*)d_in[2];
    float*       out   = (float*)d_out;
    float*       S     = (float*)d_ws;      // N_*C_ = 16384 floats

    persample_sums<<<(N_ * C_) / 4, 256, 0, stream>>>(x, S);
    stats_apply<<<(N_ * C_) / 8, 256, 0, stream>>>(x, S, gamma, beta, out);
    (void)in_sizes; (void)n_in; (void)out_size; (void)ws_size;
}